// Round 10
// baseline (225.772 us; speedup 1.0000x reference)
//
#include <hip/hip_runtime.h>
#include <math.h>

// B=8, T=2048, E=256, H=8, D=32, F=1024
#define TT 2048
#define TE 256
#define NTOK 16384
// Q pre-scale: 256^-0.5 * log2(e)  (so softmax exp == exp2 of scores)
#define QSCALE (0.0625f * 1.44269504088896f)

typedef short  bf16x8 __attribute__((ext_vector_type(8)));
typedef float  f32x4  __attribute__((ext_vector_type(4)));
typedef float  f32x16 __attribute__((ext_vector_type(16)));
typedef unsigned short u16x4 __attribute__((ext_vector_type(4)));
typedef unsigned short u16x8 __attribute__((ext_vector_type(8)));

__device__ __forceinline__ unsigned short f2b(float f) {
    union { float f; unsigned int u; } v; v.f = f;
    unsigned int r = v.u + 0x7FFF + ((v.u >> 16) & 1);   // RNE
    return (unsigned short)(r >> 16);
}
__device__ __forceinline__ float b2f(unsigned short u) {
    union { unsigned int i; float f; } v; v.i = ((unsigned int)u) << 16;
    return v.f;
}
#if __has_builtin(__builtin_amdgcn_cvt_pk_bf16_f32)
__device__ __forceinline__ unsigned int pk_bf16(float a, float b) {
    typedef __bf16 bf2 __attribute__((ext_vector_type(2)));
    union { bf2 v; unsigned int u; } u;
    u.v = __builtin_amdgcn_cvt_pk_bf16_f32(a, b);
    return u.u;
}
#else
__device__ __forceinline__ unsigned int pk_bf16(float a, float b) {
    return (unsigned int)f2b(a) | ((unsigned int)f2b(b) << 16);
}
#endif
// Native exp2 (single v_exp_f32) — exp2f w/o fast-math is the slow OCML path.
#if __has_builtin(__builtin_amdgcn_exp2f)
#define FEXP2(x) __builtin_amdgcn_exp2f(x)
#else
#define FEXP2(x) __expf(0.69314718056f * (x))
#endif
// permlane32_swap: exchanges hi-32 lanes of a with lo-32 lanes of b.
__device__ __forceinline__ void pswap(unsigned &a, unsigned &b) {
#if __has_builtin(__builtin_amdgcn_permlane32_swap)
    auto r = __builtin_amdgcn_permlane32_swap(a, b, false, false);
    a = r[0]; b = r[1];
#else
    asm("v_permlane32_swap_b32 %0, %1" : "+v"(a), "+v"(b));
#endif
}
__device__ __forceinline__ bf16x8 ld8(const unsigned short* p) {
    return *(const bf16x8*)p;
}
// Async global->LDS, 16B/lane. LDS dest = wave-uniform base + lane*16.
__device__ __forceinline__ void gl_lds16(const unsigned short* g, unsigned short* l) {
    __builtin_amdgcn_global_load_lds(
        (const __attribute__((address_space(1))) unsigned int*)(uintptr_t)g,
        (__attribute__((address_space(3))) unsigned int*)(uintptr_t)l,
        16, 0, 0);
}
#define MFMA16(a, b, c) __builtin_amdgcn_mfma_f32_16x16x32_bf16((a), (b), (c), 0, 0, 0)
#define MFMA32(a, b, c) __builtin_amdgcn_mfma_f32_32x32x16_bf16((a), (b), (c), 0, 0, 0)
#define SETPRIO(n) __builtin_amdgcn_s_setprio(n)

// ===========================================================================
// Round 10: GEMMs rebuilt at BM=64 x BN=128 (4 waves 2x2, wave-tile 32x64,
// acc[2][4]) to DOUBLE block residency: proj/ffn2 256->512 blocks (1->2 /CU),
// qkv 768->1536 (3->6), ffn1 1024->2048 (4->8). A-traffic unchanged (same
// n-tile count per A-row); extra B re-reads are L2-resident weights. Counted
// vmcnt(3) (3 loads/wave/stage: 1 A + 2 B). LDS 36KB (3-buf). Attention,
// prep, ln2_red byte-identical to round 9.
// ===========================================================================

// softmax(st) -> bf16 P-fragments -> PV MFMAs, in-register (T12).
__device__ __forceinline__ void soft_pv(const f32x16 st, bf16x8 vv0, bf16x8 vv1,
                                        bool diag, int hi, int l31, f32x16& acc) {
    unsigned Wd[8];
    if (diag) {                        // mask: s_local <= t_local
#pragma unroll
        for (int j = 0; j < 8; ++j) {
            int r0 = 2 * j;
            int s0 = (r0 & 3) + 8 * (r0 >> 2) + 4 * hi;
            float e0 = (s0 <= l31)     ? FEXP2(st[r0])     : 0.f;
            float e1 = (s0 + 1 <= l31) ? FEXP2(st[r0 + 1]) : 0.f;
            Wd[j] = pk_bf16(e0, e1);
        }
    } else {
#pragma unroll
        for (int j = 0; j < 8; ++j)
            Wd[j] = pk_bf16(FEXP2(st[2 * j]), FEXP2(st[2 * j + 1]));
    }
    pswap(Wd[0], Wd[2]); pswap(Wd[1], Wd[3]);
    pswap(Wd[4], Wd[6]); pswap(Wd[5], Wd[7]);
    union { unsigned u4[4]; bf16x8 v; } pa0, pa1;
    pa0.u4[0] = Wd[0]; pa0.u4[1] = Wd[1]; pa0.u4[2] = Wd[2]; pa0.u4[3] = Wd[3];
    pa1.u4[0] = Wd[4]; pa1.u4[1] = Wd[5]; pa1.u4[2] = Wd[6]; pa1.u4[3] = Wd[7];
    SETPRIO(1);
    acc = MFMA32(pa0.v, vv0, acc);
    acc = MFMA32(pa1.v, vv1, acc);
    SETPRIO(0);
}

// exp2-accumulate for the column-sum pass.
__device__ __forceinline__ void accum_exp(const f32x16 st, bool diag,
                                          int hi, int l31, float* acc) {
    if (diag) {
#pragma unroll
        for (int r = 0; r < 16; ++r) {
            int s_local = (r & 3) + 8 * (r >> 2) + 4 * hi;
            acc[r] += (l31 >= s_local) ? FEXP2(st[r]) : 0.f;
        }
    } else {
#pragma unroll
        for (int r = 0; r < 16; ++r) acc[r] += FEXP2(st[r]);
    }
}

// ---------------------------------------------------------------------------
// prep = conv_w (blocks 0..3071) + layernorm1 (blocks 3072..7167), fused.
__global__ __launch_bounds__(256) void prep(const float* __restrict__ wq,
                                            const float* __restrict__ wk,
                                            const float* __restrict__ wv,
                                            const float* __restrict__ w_lin,
                                            const float* __restrict__ w_f1,
                                            const float* __restrict__ w_f2,
                                            unsigned short* __restrict__ Wqkv,
                                            unsigned short* __restrict__ Wlin,
                                            unsigned short* __restrict__ Wf1,
                                            unsigned short* __restrict__ Wf2,
                                            const float* __restrict__ X,
                                            const float* __restrict__ g,
                                            const float* __restrict__ bta,
                                            unsigned short* __restrict__ Yb) {
    if (blockIdx.x >= 3072) {                 // LayerNorm1 part
        int row = (blockIdx.x - 3072) * 4 + (threadIdx.x >> 6);
        int lane = threadIdx.x & 63;
        const float4 v = *(const float4*)&X[(size_t)row * TE + lane * 4];
        float s = v.x + v.y + v.z + v.w;
        float s2 = v.x * v.x + v.y * v.y + v.z * v.z + v.w * v.w;
#pragma unroll
        for (int off = 1; off <= 32; off <<= 1) {
            s  += __shfl_xor(s,  off, 64);
            s2 += __shfl_xor(s2, off, 64);
        }
        float mean = s * (1.0f / TE);
        float var = s2 * (1.0f / TE) - mean * mean;
        float rstd = rsqrtf(var + 1e-5f);
        const float4 gg = *(const float4*)&g[lane * 4];
        const float4 bb = *(const float4*)&bta[lane * 4];
        u16x4 ob = { f2b((v.x - mean) * rstd * gg.x + bb.x),
                     f2b((v.y - mean) * rstd * gg.y + bb.y),
                     f2b((v.z - mean) * rstd * gg.z + bb.z),
                     f2b((v.w - mean) * rstd * gg.w + bb.w) };
        *(u16x4*)&Yb[(size_t)row * TE + lane * 4] = ob;
        return;
    }
    int idx = blockIdx.x * 256 + threadIdx.x;  // weight convert/transpose
    if (idx < 196608) {                       // Wqkv_t [768][256]
        int n = idx >> 8, k = idx & 255;
        int which = n >> 8, h = (n >> 5) & 7, d = n & 31;
        const float* w = (which == 0) ? wq : (which == 1) ? wk : wv;
        Wqkv[idx] = f2b(w[(h * 256 + k) * 32 + d]);
    } else if (idx < 262144) {                // Wlin_t [256][256]
        int i = idx - 196608; int n = i >> 8, k = i & 255;
        Wlin[i] = f2b(w_lin[k * 256 + n]);
    } else if (idx < 524288) {                // Wf1_t [1024][256]
        int i = idx - 262144; int n = i >> 8, k = i & 255;
        Wf1[i] = f2b(w_f1[k * 1024 + n]);
    } else {                                  // Wf2_t [256][1024]
        int i = idx - 524288; int n = i >> 10, k = i & 1023;
        Wf2[i] = f2b(w_f2[k * 256 + n]);
    }
}

// ---------------------------------------------------------------------------
// Fused proj-LN2: xl = Pp + b_lin (single fp32 slice); x2 = LN(xl) -> bf16
__global__ __launch_bounds__(256) void ln2_red(const float* __restrict__ Pp,
                                               const float* __restrict__ bias,
                                               const float* __restrict__ g,
                                               const float* __restrict__ bta,
                                               unsigned short* __restrict__ Yb) {
    int row = blockIdx.x * 4 + (threadIdx.x >> 6);
    int lane = threadIdx.x & 63;
    size_t base = (size_t)row * TE + lane * 4;
    const float4 p0 = *(const float4*)&Pp[base];
    const float4 bl = *(const float4*)&bias[lane * 4];
    float4 v;
    v.x = p0.x + bl.x; v.y = p0.y + bl.y;
    v.z = p0.z + bl.z; v.w = p0.w + bl.w;
    float s = v.x + v.y + v.z + v.w;
    float s2 = v.x * v.x + v.y * v.y + v.z * v.z + v.w * v.w;
#pragma unroll
    for (int off = 1; off <= 32; off <<= 1) {
        s  += __shfl_xor(s,  off, 64);
        s2 += __shfl_xor(s2, off, 64);
    }
    float mean = s * (1.0f / TE);
    float var = s2 * (1.0f / TE) - mean * mean;
    float rstd = rsqrtf(var + 1e-5f);
    const float4 gg = *(const float4*)&g[lane * 4];
    const float4 bb = *(const float4*)&bta[lane * 4];
    u16x4 ob = { f2b((v.x - mean) * rstd * gg.x + bb.x),
                 f2b((v.y - mean) * rstd * gg.y + bb.y),
                 f2b((v.z - mean) * rstd * gg.z + bb.z),
                 f2b((v.w - mean) * rstd * gg.w + bb.w) };
    *(u16x4*)&Yb[base] = ob;
}

// ---------------------------------------------------------------------------
// LDS-staged bf16 MFMA GEMM, counted-vmcnt 3-buffer pipeline.
// Block 64x128 (2x2 waves, 32x64 wave tile), BK=32, global_load_lds w=16.
// Per K-step per wave: 1 A-slice + 2 B-slices -> steady vmcnt(3).
// Epilogue: LDS bounce -> coalesced stores; optional bias / relu / bf16
// residual add (resid: out = acc + bias + resid, used by fused ffn2).
template<int KS>
__global__ __launch_bounds__(256) void gemm_lds(const unsigned short* __restrict__ A,
                                                int lda,
                                                const unsigned short* __restrict__ Bt,
                                                int ldb,
                                                const float* __restrict__ bias,
                                                const unsigned short* __restrict__ resid,
                                                float* __restrict__ outF,
                                                unsigned short* __restrict__ outB,
                                                int N, int relu) {
    __shared__ unsigned short LDSb[3 * 2048 + 3 * 4096];   // 36 KB
    unsigned short* Al = LDSb;                 // [3][64*32]
    unsigned short* Bl = LDSb + 3 * 2048;      // [3][128*32]
    int tid = threadIdx.x;
    int w = tid >> 6, lane = tid & 63, q = lane >> 4, col = lane & 15;
    int wm = w & 1, wn = w >> 1;
    int m0 = blockIdx.x * 64;
    int n0 = blockIdx.y * 128;
    f32x4 acc[2][4] = {};
    // Staging: wave w owns A-rows [16w,16w+16) (1 load), B-rows [32w,32w+32)
    // (2 loads); source k-chunk pre-swizzled (involution with ds_read side).
    int srow = lane >> 2;                      // 0..15
    int skq  = ((lane & 3) ^ ((srow >> 1) & 3)) * 8;
    const unsigned short* Ag0 = A  + (size_t)(m0 + w * 16 + srow) * lda + skq;
    const unsigned short* Bg0 = Bt + (size_t)(n0 + w * 32 + srow) * ldb + skq;
    const unsigned short* Bg1 = Bg0 + (size_t)16 * ldb;
    int rq = (q ^ ((col >> 1) & 3)) * 8;
#define G_STAGE(bf, kk) do { \
        gl_lds16(Ag0 + (kk), &Al[(bf) * 2048 + (w * 16) * 32]); \
        gl_lds16(Bg0 + (kk), &Bl[(bf) * 4096 + (w * 32) * 32]); \
        gl_lds16(Bg1 + (kk), &Bl[(bf) * 4096 + (w * 32 + 16) * 32]); \
    } while (0)
    G_STAGE(0, 0);
    G_STAGE(1, 32);
#pragma unroll
    for (int k0 = 0; k0 < KS; k0 += 32) {
        const int jb = (k0 >> 5) % 3;
        if (k0 + 32 < KS) { asm volatile("s_waitcnt vmcnt(3)" ::: "memory"); }
        else              { asm volatile("s_waitcnt vmcnt(0)" ::: "memory"); }
        __builtin_amdgcn_s_barrier();          // raw barrier: no implicit drain
        if (k0 + 64 < KS) G_STAGE((jb + 2) % 3, k0 + 64);
        bf16x8 a[2], b[4];
#pragma unroll
        for (int i = 0; i < 2; ++i)
            a[i] = ld8(&Al[jb * 2048 + (wm * 32 + i * 16 + col) * 32 + rq]);
#pragma unroll
        for (int j = 0; j < 4; ++j)
            b[j] = ld8(&Bl[jb * 4096 + (wn * 64 + j * 16 + col) * 32 + rq]);
#pragma unroll
        for (int i = 0; i < 2; ++i)
#pragma unroll
            for (int j = 0; j < 4; ++j)
                acc[i][j] = MFMA16(a[i], b[j], acc[i][j]);
        __builtin_amdgcn_sched_barrier(0);     // pin MFMA/lgkm before next bar;
                                               // keep epilogue out of the
                                               // counted-vmcnt region
    }
#undef G_STAGE
    // ---- epilogue: LDS bounce -> coalesced stores -------------------------
    float* Cb = (float*)LDSb;                  // 32 x 132 f32 = 16.9 KB
    const int CLD = 132;                       // +4 pad: 2-way banks max
#pragma unroll
    for (int i = 0; i < 2; ++i) {
        __syncthreads();                       // prev use of LDS done
#pragma unroll
        for (int j = 0; j < 4; ++j)
#pragma unroll
            for (int r = 0; r < 4; ++r)
                Cb[(wm * 16 + q * 4 + r) * CLD + wn * 64 + j * 16 + col] = acc[i][j][r];
        __syncthreads();
        int row = tid >> 3;                    // 0..31
        int seg = (tid & 7) * 16;              // n-local start
        int mloc = (row & 15) + i * 16 + (row >> 4) * 32;
        int m = m0 + mloc;
        int n = n0 + seg;
        float vbuf[16];
#pragma unroll
        for (int u = 0; u < 16; ++u) vbuf[u] = Cb[row * CLD + seg + u];
        if (bias) {
#pragma unroll
            for (int u4 = 0; u4 < 4; ++u4) {
                float4 bb = *(const float4*)&bias[n + u4 * 4];
                vbuf[u4 * 4 + 0] += bb.x; vbuf[u4 * 4 + 1] += bb.y;
                vbuf[u4 * 4 + 2] += bb.z; vbuf[u4 * 4 + 3] += bb.w;
            }
        }
        if (resid) {                           // fused residual (bf16)
            u16x8 r0 = *(const u16x8*)&resid[(size_t)m * N + n];
            u16x8 r1 = *(const u16x8*)&resid[(size_t)m * N + n + 8];
#pragma unroll
            for (int u = 0; u < 8; ++u) {
                vbuf[u]     += b2f(r0[u]);
                vbuf[8 + u] += b2f(r1[u]);
            }
        }
        if (relu) {
#pragma unroll
            for (int u = 0; u < 16; ++u) vbuf[u] = fmaxf(vbuf[u], 0.f);
        }
        if (outF) {
#pragma unroll
            for (int u = 0; u < 16; u += 4)
                *(float4*)&outF[(size_t)m * N + n + u] = *(const float4*)&vbuf[u];
        }
        if (outB) {
            u16x8 o0, o1;
#pragma unroll
            for (int u = 0; u < 8; ++u) { o0[u] = f2b(vbuf[u]); o1[u] = f2b(vbuf[8 + u]); }
            *(u16x8*)&outB[(size_t)m * N + n] = o0;
            *(u16x8*)&outB[(size_t)m * N + n + 8] = o1;
        }
    }
}

// ---------------------------------------------------------------------------
// QKV GEMM, same 64x128 counted-vmcnt core (K=256). Epilogue scatter into the
// coalescing layouts: Qd/Kd [bh][db][t][16] (Q x QSCALE), Vc [bh][s/8][d][s%8].
__global__ __launch_bounds__(256) void gemm_qkv(const unsigned short* __restrict__ A,
                                                const unsigned short* __restrict__ Bt,
                                                unsigned short* __restrict__ Qd,
                                                unsigned short* __restrict__ Kd,
                                                unsigned short* __restrict__ Vc) {
    const int K = 256;
    __shared__ unsigned short LDSb[3 * 2048 + 3 * 4096];   // 36 KB
    unsigned short* Al = LDSb;
    unsigned short* Bl = LDSb + 3 * 2048;
    int tid = threadIdx.x;
    int w = tid >> 6, lane = tid & 63, q = lane >> 4, col = lane & 15;
    int wm = w & 1, wn = w >> 1;
    int m0 = blockIdx.x * 64;
    int n0 = blockIdx.y * 128;
    f32x4 acc[2][4] = {};
    int srow = lane >> 2;
    int skq  = ((lane & 3) ^ ((srow >> 1) & 3)) * 8;
    const unsigned short* Ag0 = A  + (size_t)(m0 + w * 16 + srow) * K + skq;
    const unsigned short* Bg0 = Bt + (size_t)(n0 + w * 32 + srow) * K + skq;
    const unsigned short* Bg1 = Bg0 + (size_t)16 * K;
    int rq = (q ^ ((col >> 1) & 3)) * 8;
#define G_STAGE(bf, kk) do { \
        gl_lds16(Ag0 + (kk), &Al[(bf) * 2048 + (w * 16) * 32]); \
        gl_lds16(Bg0 + (kk), &Bl[(bf) * 4096 + (w * 32) * 32]); \
        gl_lds16(Bg1 + (kk), &Bl[(bf) * 4096 + (w * 32 + 16) * 32]); \
    } while (0)
    G_STAGE(0, 0);
    G_STAGE(1, 32);
#pragma unroll
    for (int k0 = 0; k0 < K; k0 += 32) {
        const int jb = (k0 >> 5) % 3;
        if (k0 + 32 < K) { asm volatile("s_waitcnt vmcnt(3)" ::: "memory"); }
        else             { asm volatile("s_waitcnt vmcnt(0)" ::: "memory"); }
        __builtin_amdgcn_s_barrier();
        if (k0 + 64 < K) G_STAGE((jb + 2) % 3, k0 + 64);
        bf16x8 a[2], b[4];
#pragma unroll
        for (int i = 0; i < 2; ++i)
            a[i] = ld8(&Al[jb * 2048 + (wm * 32 + i * 16 + col) * 32 + rq]);
#pragma unroll
        for (int j = 0; j < 4; ++j)
            b[j] = ld8(&Bl[jb * 4096 + (wn * 64 + j * 16 + col) * 32 + rq]);
#pragma unroll
        for (int i = 0; i < 2; ++i)
#pragma unroll
            for (int j = 0; j < 4; ++j)
                acc[i][j] = MFMA16(a[i], b[j], acc[i][j]);
        __builtin_amdgcn_sched_barrier(0);
    }
#undef G_STAGE
#pragma unroll
    for (int i = 0; i < 2; ++i)
#pragma unroll
    for (int j = 0; j < 4; ++j) {
        int n = n0 + wn * 64 + j * 16 + col;
        int which = n >> 8, h = (n >> 5) & 7, d = n & 31;
        int m = m0 + wm * 32 + i * 16 + q * 4;
        int b = m >> 11, t = m & 2047;
        int bh = b * 8 + h;
        if (which == 0) {
            size_t qb = ((size_t)(bh * 2 + (d >> 4)) * TT + t) * 16 + (d & 15);
#pragma unroll
            for (int r = 0; r < 4; ++r)
                Qd[qb + r * 16] = f2b(acc[i][j][r] * QSCALE);
        } else if (which == 1) {
            size_t kb = ((size_t)(bh * 2 + (d >> 4)) * TT + t) * 16 + (d & 15);
#pragma unroll
            for (int r = 0; r < 4; ++r)
                Kd[kb + r * 16] = f2b(acc[i][j][r]);
        } else {
            uint2 pv;
            pv.x = pk_bf16(acc[i][j][0], acc[i][j][1]);
            pv.y = pk_bf16(acc[i][j][2], acc[i][j][3]);
            *(uint2*)&Vc[(((size_t)bh * 256 + (t >> 3)) * 32 + d) * 8 + (t & 7)] = pv;
        }
    }
}

// ---------------------------------------------------------------------------
// Pass 1 (+ fused V scale), 2-deep pipelined: colsum[s] = sum_{t>=s} exp2(.);
// then scale Vc columns in-place. (byte-identical to round 9)
__global__ __launch_bounds__(256, 2) void attn_cols(const unsigned short* __restrict__ Qd,
                                                    const unsigned short* __restrict__ Kd,
                                                    unsigned short* __restrict__ Vc) {
    __shared__ float Lb[4][32];
    __shared__ float Linv[32];
    int tid = threadIdx.x;
    int w = tid >> 6, lane = tid & 63, hi = lane >> 5, l31 = lane & 31;
    int bh = blockIdx.x;
    int u = blockIdx.y;                       // 0..31
    const unsigned short* Qb = Qd + ((size_t)bh * 2 * TT + l31) * 16 + hi * 8;
    const unsigned short* Kb = Kd + ((size_t)bh * 2 * TT + l31) * 16 + hi * 8;
    const f32x16 z16 = {};
#pragma unroll
    for (int phase = 0; phase < 2; ++phase) {
        int stile = phase ? (63 - u) : u;
        int sbase = stile * 32;
        bf16x8 a0 = ld8(Kb + (size_t)sbase * 16);             // d 0..15
        bf16x8 a1 = ld8(Kb + ((size_t)TT + sbase) * 16);      // d 16..31
        float acc[16] = {};
        int c = stile + w;
        bool diagP = (w == 0);                 // first chunk is diag for wave 0
        bf16x8 qP0, qP1, qQ0, qQ1;
        if (c < 64) {
            qP0 = ld8(Qb + (size_t)(c * 32) * 16);
            qP1 = ld8(Qb + ((size_t)TT + c * 32) * 16);
        }
        if (c + 4 < 64) {
            qQ0 = ld8(Qb + (size_t)((c + 4) * 32) * 16);
            qQ1 = ld8(Qb + ((size_t)TT + (c + 4) * 32) * 16);
        }
        while (c + 8 < 64) {                   // P, Q, and next-P all exist
            SETPRIO(1);
            f32x16 stP = MFMA32(a0, qP0, z16); stP = MFMA32(a1, qP1, stP);
            SETPRIO(0);
            qP0 = ld8(Qb + (size_t)((c + 8) * 32) * 16);        // next-P loads
            qP1 = ld8(Qb + ((size_t)TT + (c + 8) * 32) * 16);
            SETPRIO(1);
            f32x16 stQ = MFMA32(a0, qQ0, z16); stQ = MFMA32(a1, qQ1, stQ);
            SETPRIO(0);
            accum_exp(stP, diagP, hi, l31, acc); diagP = false; // VALU under stQ
            if (c + 12 < 64) {
                qQ0 = ld8(Qb + (size_t)((c + 12) * 32) * 16);   // next-Q loads
                qQ1 = ld8(Qb + ((size_t)TT + (c + 12) * 32) * 16);
            }
            accum_exp(stQ, false, hi, l31, acc);
            c += 8;
        }
        if (c < 64) {
            f32x16 stP = MFMA32(a0, qP0, z16); stP = MFMA32(a1, qP1, stP);
            accum_exp(stP, diagP, hi, l31, acc);
        }
        if (c + 4 < 64) {
            f32x16 stQ = MFMA32(a0, qQ0, z16); stQ = MFMA32(a1, qQ1, stQ);
            accum_exp(stQ, false, hi, l31, acc);
        }
#pragma unroll
        for (int off = 1; off <= 16; off <<= 1)
#pragma unroll
            for (int r = 0; r < 16; ++r) acc[r] += __shfl_xor(acc[r], off, 64);
        if (l31 == 0) {
#pragma unroll
            for (int r = 0; r < 16; ++r) {
                int s_local = (r & 3) + 8 * (r >> 2) + 4 * hi;
                Lb[w][s_local] = acc[r];
            }
        }
        __syncthreads();
        if (tid < 32)
            Linv[tid] = 1.0f / (Lb[0][tid] + Lb[1][tid] + Lb[2][tid] + Lb[3][tid]);
        __syncthreads();
        // scale Vc for s in [sbase, sbase+32): 4 sb x 32 d rows of 8
        if (tid < 128) {
            int sbl = tid >> 5;                // 0..3
            int d = tid & 31;
            size_t base = (((size_t)bh * 256 + stile * 4 + sbl) * 32 + d) * 8;
            u16x8 v = *(const u16x8*)&Vc[base];
            u16x8 o;
#pragma unroll
            for (int e = 0; e < 8; ++e) o[e] = f2b(b2f(v[e]) * Linv[sbl * 8 + e]);
            *(u16x8*)&Vc[base] = o;
        }
        __syncthreads();                       // Lb/Linv reused next phase
    }
}

// ---------------------------------------------------------------------------
// Pass 2: O[t,:] = sum_{s<=t} exp2(q_t.k_s) * V'[s,:], xh = bf16(xn + O).
// (byte-identical to round 9)
__global__ __launch_bounds__(256, 2) void attn_out(const unsigned short* __restrict__ Qd,
                                                   const unsigned short* __restrict__ Kd,
                                                   const unsigned short* __restrict__ Vc,
                                                   const unsigned short* __restrict__ xnb,
                                                   unsigned short* __restrict__ xh_bf) {
    __shared__ float Ob[4][16][36];            // 9216 B
    int tid = threadIdx.x;
    int w = tid >> 6, lane = tid & 63, hi = lane >> 5, l31 = lane & 31;
    int bh = blockIdx.x, b = bh >> 3, h = bh & 7;
    int u = blockIdx.y;                        // 0..31
    const unsigned short* Kb = Kd + ((size_t)bh * 2 * TT + l31) * 16 + hi * 8;
    const unsigned short* Vb = Vc + (size_t)bh * 65536 + hi * 256 + l31 * 8;
    const unsigned short* Qbase = Qd + ((size_t)bh * 2 * TT + l31) * 16 + hi * 8;
    const f32x16 z16 = {};

#pragma unroll
    for (int phase = 0; phase < 2; ++phase) {
        int tt = phase ? (63 - u) : u;
        int tbase = tt * 32;
        bf16x8 q0 = ld8(Qbase + (size_t)tbase * 16);          // d 0..15
        bf16x8 q1 = ld8(Qbase + ((size_t)TT + tbase) * 16);   // d 16..31
        f32x16 acc = z16;                      // O[t=(r&3)+8(r>>2)+4hi][d=l31]

        int c = w;
        bf16x8 kP0, kP1, vP0, vP1, kQ0, kQ1, vQ0, vQ1;
        if (c <= tt) {
            kP0 = ld8(Kb + (size_t)c * 512);
            kP1 = ld8(Kb + (size_t)TT * 16 + (size_t)c * 512);
            vP0 = ld8(Vb + (size_t)c * 1024);
            vP1 = ld8(Vb + (size_t)c * 1024 + 512);
        }
        if (c + 4 <= tt) {
            kQ0 = ld8(Kb + (size_t)(c + 4) * 512);
            kQ1 = ld8(Kb + (size_t)TT * 16 + (size_t)(c + 4) * 512);
            vQ0 = ld8(Vb + (size_t)(c + 4) * 1024);
            vQ1 = ld8(Vb + (size_t)(c + 4) * 1024 + 512);
        }
        while (c + 8 <= tt) {                  // P,Q non-diag; next-P exists
            SETPRIO(1);
            f32x16 stP = MFMA32(kP0, q0, z16); stP = MFMA32(kP1, q1, stP);
            SETPRIO(0);
            kP0 = ld8(Kb + (size_t)(c + 8) * 512);              // next-P loads
            kP1 = ld8(Kb + (size_t)TT * 16 + (size_t)(c + 8) * 512);
            SETPRIO(1);
            f32x16 stQ = MFMA32(kQ0, q0, z16); stQ = MFMA32(kQ1, q1, stQ);
            SETPRIO(0);
            soft_pv(stP, vP0, vP1, false, hi, l31, acc);        // VALU under stQ
            vP0 = ld8(Vb + (size_t)(c + 8) * 1024);
            vP1 = ld8(Vb + (size_t)(c + 8) * 1024 + 512);
            if (c + 12 <= tt) {
                kQ0 = ld8(Kb + (size_t)(c + 12) * 512);         // next-Q loads
                kQ1 = ld8(Kb + (size_t)TT * 16 + (size_t)(c + 12) * 512);
            }
            soft_pv(stQ, vQ0, vQ1, false, hi, l31, acc);        // PV under loads
            if (c + 12 <= tt) {
                vQ0 = ld8(Vb + (size_t)(c + 12) * 1024);
                vQ1 = ld8(Vb + (size_t)(c + 12) * 1024 + 512);
            }
            c += 8;
        }
        if (c <= tt) {                         // tail chunk 1 (maybe diag)
            f32x16 stP = MFMA32(kP0, q0, z16); stP = MFMA32(kP1, q1, stP);
            soft_pv(stP, vP0, vP1, c == tt, hi, l31, acc);
        }
        if (c + 4 <= tt) {                     // tail chunk 2 (maybe diag)
            f32x16 stQ = MFMA32(kQ0, q0, z16); stQ = MFMA32(kQ1, q1, stQ);
            soft_pv(stQ, vQ0, vQ1, c + 4 == tt, hi, l31, acc);
        }

        // Two half-tile combines: t-rows [0,16) from acc r 0..7, then
        // t-rows [16,32) from acc r 8..15.
#pragma unroll
        for (int half = 0; half < 2; ++half) {
#pragma unroll
            for (int rr = 0; rr < 8; ++rr) {
                int r = half * 8 + rr;
                int t16 = (r & 3) + 8 * ((r >> 2) & 1) + 4 * hi;  // 0..15
                Ob[w][t16][l31] = acc[r];
            }
            __syncthreads();
            if (tid < 128) {                   // 16 rows x 8 col-quads
                int row = tid >> 3;
                int c4 = (tid & 7) * 4;
                float4 s0 = *(const float4*)&Ob[0][row][c4];
                float4 s1 = *(const float4*)&Ob[1][row][c4];
                float4 s2 = *(const float4*)&Ob[2][row][c4];
                float4 s3 = *(const float4*)&Ob[3][row][c4];
                size_t base = ((size_t)(b * TT) + tbase + half * 16 + row) * TE
                              + h * 32 + c4;
                u16x4 xv = *(const u16x4*)&xnb[base];
                u16x4 ob = { f2b(s0.x + s1.x + s2.x + s3.x + b2f(xv[0])),
                             f2b(s0.y + s1.y + s2.y + s3.y + b2f(xv[1])),
                             f2b(s0.z + s1.z + s2.z + s3.z + b2f(xv[2])),
                             f2b(s0.w + s1.w + s2.w + s3.w + b2f(xv[3])) };
                *(u16x4*)&xh_bf[base] = ob;
            }
            __syncthreads();                   // Ob reused next half/phase
        }
    }
}

// ---------------------------------------------------------------------------
extern "C" void kernel_launch(void* const* d_in, const int* in_sizes, int n_in,
                              void* d_out, int out_size, void* d_ws, size_t ws_size,
                              hipStream_t stream) {
    (void)in_sizes; (void)n_in; (void)out_size; (void)ws_size;
    const float* x     = (const float*)d_in[0];
    const float* wq    = (const float*)d_in[1];
    const float* wk    = (const float*)d_in[2];
    const float* wv    = (const float*)d_in[3];
    const float* w_lin = (const float*)d_in[4];
    const float* b_lin = (const float*)d_in[5];
    const float* g1    = (const float*)d_in[6];
    const float* beta1 = (const float*)d_in[7];
    const float* g2    = (const float*)d_in[8];
    const float* beta2 = (const float*)d_in[9];
    const float* w_f1  = (const float*)d_in[10];
    const float* b_f1  = (const float*)d_in[11];
    const float* w_f2  = (const float*)d_in[12];
    const float* b_f2  = (const float*)d_in[13];
    float* out = (float*)d_out;

    // Workspace layout (bytes), max 74 MB:
    char* ws = (char*)d_ws;
    unsigned short* Wqkv_t = (unsigned short*)(ws + 0);         //  384 KB
    unsigned short* Wlin_t = (unsigned short*)(ws + 393216);    //  128 KB
    unsigned short* Wf1_t  = (unsigned short*)(ws + 524288);    //  512 KB
    unsigned short* Wf2_t  = (unsigned short*)(ws + 1048576);   //  512 KB
    unsigned short* xn_bf  = (unsigned short*)(ws + 2097152);   //    8 MB [x2_bf aliases]
    unsigned short* Qbf    = (unsigned short*)(ws + 10485760);  //    8 MB ┐
    unsigned short* Kbf    = (unsigned short*)(ws + 18874368);  //    8 MB ├ h_bf (32 MB) aliases
    unsigned short* Vt     = (unsigned short*)(ws + 27262976);  //    8 MB │ (in-place scale)
    unsigned short* xh_bf  = (unsigned short*)(ws + 35651584);  //    8 MB ┘
    float*          Pp     = (float*)(ws + 44040192);           // 16.7 MB proj fp32 (single slice)
    unsigned short* x2_bf  = xn_bf;
    unsigned short* h_bf   = Qbf;   // 32 MB spanning Qbf..xh_bf (dead by FFN1)

    prep<<<7168, 256, 0, stream>>>(wq, wk, wv, w_lin, w_f1, w_f2,
                                   Wqkv_t, Wlin_t, Wf1_t, Wf2_t,
                                   x, g1, beta1, xn_bf);
    gemm_qkv<<<dim3(256, 6), 256, 0, stream>>>(xn_bf, Wqkv_t, Qbf, Kbf, Vt);
    attn_cols<<<dim3(64, 32), 256, 0, stream>>>(Qbf, Kbf, Vt);
    attn_out<<<dim3(64, 32), 256, 0, stream>>>(Qbf, Kbf, Vt, xn_bf, xh_bf);
    // proj: no split-K, single fp32 slice (bias folded into ln2_red)
    gemm_lds<256><<<dim3(256, 2), 256, 0, stream>>>(xh_bf, 256, Wlin_t, 256,
                                                    nullptr, nullptr, Pp, nullptr, 256, 0);
    ln2_red<<<4096, 256, 0, stream>>>(Pp, b_lin, g2, beta2, x2_bf);
    gemm_lds<256><<<dim3(256, 8), 256, 0, stream>>>(x2_bf, 256, Wf1_t, 256,
                                                    b_f1, nullptr, nullptr, h_bf, 1024, 1);
    // ffn2: K=1024 single pass, fused epilogue out = acc + b_f2 + x2 (fp32)
    gemm_lds<1024><<<dim3(256, 2), 256, 0, stream>>>(h_bf, 1024, Wf2_t, 1024,
                                                     b_f2, x2_bf, out, nullptr, 256, 0);
}

// Round 11
// 222.408 us; speedup vs baseline: 1.0151x; 1.0151x over previous
//
#include <hip/hip_runtime.h>
#include <math.h>

// B=8, T=2048, E=256, H=8, D=32, F=1024
#define TT 2048
#define TE 256
#define NTOK 16384
// Q pre-scale: 256^-0.5 * log2(e)  (so softmax exp == exp2 of scores)
#define QSCALE (0.0625f * 1.44269504088896f)

typedef short  bf16x8 __attribute__((ext_vector_type(8)));
typedef float  f32x4  __attribute__((ext_vector_type(4)));
typedef float  f32x16 __attribute__((ext_vector_type(16)));
typedef unsigned short u16x4 __attribute__((ext_vector_type(4)));
typedef unsigned short u16x8 __attribute__((ext_vector_type(8)));

__device__ __forceinline__ unsigned short f2b(float f) {
    union { float f; unsigned int u; } v; v.f = f;
    unsigned int r = v.u + 0x7FFF + ((v.u >> 16) & 1);   // RNE
    return (unsigned short)(r >> 16);
}
__device__ __forceinline__ float b2f(unsigned short u) {
    union { unsigned int i; float f; } v; v.i = ((unsigned int)u) << 16;
    return v.f;
}
#if __has_builtin(__builtin_amdgcn_cvt_pk_bf16_f32)
__device__ __forceinline__ unsigned int pk_bf16(float a, float b) {
    typedef __bf16 bf2 __attribute__((ext_vector_type(2)));
    union { bf2 v; unsigned int u; } u;
    u.v = __builtin_amdgcn_cvt_pk_bf16_f32(a, b);
    return u.u;
}
#else
__device__ __forceinline__ unsigned int pk_bf16(float a, float b) {
    return (unsigned int)f2b(a) | ((unsigned int)f2b(b) << 16);
}
#endif
// Native exp2 (single v_exp_f32) — exp2f w/o fast-math is the slow OCML path.
#if __has_builtin(__builtin_amdgcn_exp2f)
#define FEXP2(x) __builtin_amdgcn_exp2f(x)
#else
#define FEXP2(x) __expf(0.69314718056f * (x))
#endif
// permlane32_swap: exchanges hi-32 lanes of a with lo-32 lanes of b.
__device__ __forceinline__ void pswap(unsigned &a, unsigned &b) {
#if __has_builtin(__builtin_amdgcn_permlane32_swap)
    auto r = __builtin_amdgcn_permlane32_swap(a, b, false, false);
    a = r[0]; b = r[1];
#else
    asm("v_permlane32_swap_b32 %0, %1" : "+v"(a), "+v"(b));
#endif
}
__device__ __forceinline__ bf16x8 ld8(const unsigned short* p) {
    return *(const bf16x8*)p;
}
// Async global->LDS, 16B/lane. LDS dest = wave-uniform base + lane*16.
__device__ __forceinline__ void gl_lds16(const unsigned short* g, unsigned short* l) {
    __builtin_amdgcn_global_load_lds(
        (const __attribute__((address_space(1))) unsigned int*)(uintptr_t)g,
        (__attribute__((address_space(3))) unsigned int*)(uintptr_t)l,
        16, 0, 0);
}
#define MFMA16(a, b, c) __builtin_amdgcn_mfma_f32_16x16x32_bf16((a), (b), (c), 0, 0, 0)
#define MFMA32(a, b, c) __builtin_amdgcn_mfma_f32_32x32x16_bf16((a), (b), (c), 0, 0, 0)
#define SETPRIO(n) __builtin_amdgcn_s_setprio(n)

// ===========================================================================
// Round 11:
//  (1) prep's weight conversion was an uncoalesced transpose: consecutive
//      lanes read stride-1KB/4KB fp32 (64 lines/wave-load, 16x HBM over-fetch
//      on a cold 3MB read). Rewritten as LDS-tiled transpose (240 tile
//      blocks): coalesced fp32 reads -> LDS -> coalesced bf16 row writes.
//  (2) attention kernels phase-split: one tile per block, grid (64,64) —
//      halves per-block work, doubles schedulable blocks (tail/backfill).
// GEMMs byte-identical to round 10.
// ===========================================================================

// softmax(st) -> bf16 P-fragments -> PV MFMAs, in-register (T12).
__device__ __forceinline__ void soft_pv(const f32x16 st, bf16x8 vv0, bf16x8 vv1,
                                        bool diag, int hi, int l31, f32x16& acc) {
    unsigned Wd[8];
    if (diag) {                        // mask: s_local <= t_local
#pragma unroll
        for (int j = 0; j < 8; ++j) {
            int r0 = 2 * j;
            int s0 = (r0 & 3) + 8 * (r0 >> 2) + 4 * hi;
            float e0 = (s0 <= l31)     ? FEXP2(st[r0])     : 0.f;
            float e1 = (s0 + 1 <= l31) ? FEXP2(st[r0 + 1]) : 0.f;
            Wd[j] = pk_bf16(e0, e1);
        }
    } else {
#pragma unroll
        for (int j = 0; j < 8; ++j)
            Wd[j] = pk_bf16(FEXP2(st[2 * j]), FEXP2(st[2 * j + 1]));
    }
    pswap(Wd[0], Wd[2]); pswap(Wd[1], Wd[3]);
    pswap(Wd[4], Wd[6]); pswap(Wd[5], Wd[7]);
    union { unsigned u4[4]; bf16x8 v; } pa0, pa1;
    pa0.u4[0] = Wd[0]; pa0.u4[1] = Wd[1]; pa0.u4[2] = Wd[2]; pa0.u4[3] = Wd[3];
    pa1.u4[0] = Wd[4]; pa1.u4[1] = Wd[5]; pa1.u4[2] = Wd[6]; pa1.u4[3] = Wd[7];
    SETPRIO(1);
    acc = MFMA32(pa0.v, vv0, acc);
    acc = MFMA32(pa1.v, vv1, acc);
    SETPRIO(0);
}

// exp2-accumulate for the column-sum pass.
__device__ __forceinline__ void accum_exp(const f32x16 st, bool diag,
                                          int hi, int l31, float* acc) {
    if (diag) {
#pragma unroll
        for (int r = 0; r < 16; ++r) {
            int s_local = (r & 3) + 8 * (r >> 2) + 4 * hi;
            acc[r] += (l31 >= s_local) ? FEXP2(st[r]) : 0.f;
        }
    } else {
#pragma unroll
        for (int r = 0; r < 16; ++r) acc[r] += FEXP2(st[r]);
    }
}

// ---------------------------------------------------------------------------
// prep: blocks 0..239 = LDS-tiled weight transposes (coalesced both sides);
//       blocks 240..4335 = LayerNorm1.
__global__ __launch_bounds__(256) void prep(const float* __restrict__ wq,
                                            const float* __restrict__ wk,
                                            const float* __restrict__ wv,
                                            const float* __restrict__ w_lin,
                                            const float* __restrict__ w_f1,
                                            const float* __restrict__ w_f2,
                                            unsigned short* __restrict__ Wqkv,
                                            unsigned short* __restrict__ Wlin,
                                            unsigned short* __restrict__ Wf1,
                                            unsigned short* __restrict__ Wf2,
                                            const float* __restrict__ X,
                                            const float* __restrict__ g,
                                            const float* __restrict__ bta,
                                            unsigned short* __restrict__ Yb) {
    int bid = blockIdx.x;
    if (bid >= 240) {                         // LayerNorm1 part
        int row = (bid - 240) * 4 + (threadIdx.x >> 6);
        int lane = threadIdx.x & 63;
        const float4 v = *(const float4*)&X[(size_t)row * TE + lane * 4];
        float s = v.x + v.y + v.z + v.w;
        float s2 = v.x * v.x + v.y * v.y + v.z * v.z + v.w * v.w;
#pragma unroll
        for (int off = 1; off <= 32; off <<= 1) {
            s  += __shfl_xor(s,  off, 64);
            s2 += __shfl_xor(s2, off, 64);
        }
        float mean = s * (1.0f / TE);
        float var = s2 * (1.0f / TE) - mean * mean;
        float rstd = rsqrtf(var + 1e-5f);
        const float4 gg = *(const float4*)&g[lane * 4];
        const float4 bb = *(const float4*)&bta[lane * 4];
        u16x4 ob = { f2b((v.x - mean) * rstd * gg.x + bb.x),
                     f2b((v.y - mean) * rstd * gg.y + bb.y),
                     f2b((v.z - mean) * rstd * gg.z + bb.z),
                     f2b((v.w - mean) * rstd * gg.w + bb.w) };
        *(u16x4*)&Yb[(size_t)row * TE + lane * 4] = ob;
        return;
    }
    __shared__ unsigned short Tt[64][65];     // 8.3 KB transpose tile
    int t = threadIdx.x;
    if (bid < 96) {                           // Wqkv: 24 slices of [256k][32d]
        int which = bid / 32, h = (bid >> 2) & 7, kt = bid & 3;
        const float* src = ((which == 0) ? wq : (which == 1) ? wk : wv)
                           + (size_t)h * 256 * 32;
        int d = t & 31, kr = t >> 5;           // kr 0..7
#pragma unroll
        for (int r = 0; r < 8; ++r) {          // coalesced fp32 reads
            int kl = kr * 8 + r;
            Tt[kl][d] = f2b(src[(size_t)(kt * 64 + kl) * 32 + d]);
        }
        __syncthreads();
        int kl = t & 63, dr = t >> 6;          // dr 0..3
#pragma unroll
        for (int r = 0; r < 8; ++r) {          // coalesced bf16 row writes
            int dl = dr * 8 + r;
            Wqkv[(size_t)(which * 256 + h * 32 + dl) * 256 + kt * 64 + kl] = Tt[kl][dl];
        }
        return;
    }
    // 64x64 tile transpose for Wlin / Wf1 / Wf2
    const float* src; unsigned short* dst; int ldn, ldk, kt, nt;
    if (bid < 112)      { int b2 = bid - 96;  src = w_lin; dst = Wlin; ldn = 256;  ldk = 256;  kt = b2 & 3;  nt = b2 >> 2; }
    else if (bid < 176) { int b3 = bid - 112; src = w_f1;  dst = Wf1;  ldn = 1024; ldk = 256;  kt = b3 >> 4; nt = b3 & 15; }
    else                { int b4 = bid - 176; src = w_f2;  dst = Wf2;  ldn = 256;  ldk = 1024; kt = b4 >> 2; nt = b4 & 3; }
    int n = t & 63, kr = t >> 6;               // kr 0..3
#pragma unroll
    for (int r = 0; r < 16; ++r) {             // coalesced fp32 reads
        int kl = kr * 16 + r;
        Tt[kl][n] = f2b(src[(size_t)(kt * 64 + kl) * ldn + nt * 64 + n]);
    }
    __syncthreads();
    int klane = t & 63, nr = t >> 6;
#pragma unroll
    for (int r = 0; r < 16; ++r) {             // coalesced bf16 row writes
        int nl = nr * 16 + r;
        dst[(size_t)(nt * 64 + nl) * ldk + kt * 64 + klane] = Tt[klane][nl];
    }
}

// ---------------------------------------------------------------------------
// Fused proj-LN2: xl = Pp + b_lin (single fp32 slice); x2 = LN(xl) -> bf16
__global__ __launch_bounds__(256) void ln2_red(const float* __restrict__ Pp,
                                               const float* __restrict__ bias,
                                               const float* __restrict__ g,
                                               const float* __restrict__ bta,
                                               unsigned short* __restrict__ Yb) {
    int row = blockIdx.x * 4 + (threadIdx.x >> 6);
    int lane = threadIdx.x & 63;
    size_t base = (size_t)row * TE + lane * 4;
    const float4 p0 = *(const float4*)&Pp[base];
    const float4 bl = *(const float4*)&bias[lane * 4];
    float4 v;
    v.x = p0.x + bl.x; v.y = p0.y + bl.y;
    v.z = p0.z + bl.z; v.w = p0.w + bl.w;
    float s = v.x + v.y + v.z + v.w;
    float s2 = v.x * v.x + v.y * v.y + v.z * v.z + v.w * v.w;
#pragma unroll
    for (int off = 1; off <= 32; off <<= 1) {
        s  += __shfl_xor(s,  off, 64);
        s2 += __shfl_xor(s2, off, 64);
    }
    float mean = s * (1.0f / TE);
    float var = s2 * (1.0f / TE) - mean * mean;
    float rstd = rsqrtf(var + 1e-5f);
    const float4 gg = *(const float4*)&g[lane * 4];
    const float4 bb = *(const float4*)&bta[lane * 4];
    u16x4 ob = { f2b((v.x - mean) * rstd * gg.x + bb.x),
                 f2b((v.y - mean) * rstd * gg.y + bb.y),
                 f2b((v.z - mean) * rstd * gg.z + bb.z),
                 f2b((v.w - mean) * rstd * gg.w + bb.w) };
    *(u16x4*)&Yb[base] = ob;
}

// ---------------------------------------------------------------------------
// LDS-staged bf16 MFMA GEMM, counted-vmcnt 3-buffer pipeline.
// Block 64x128 (2x2 waves, 32x64 wave tile), BK=32, global_load_lds w=16.
template<int KS>
__global__ __launch_bounds__(256) void gemm_lds(const unsigned short* __restrict__ A,
                                                int lda,
                                                const unsigned short* __restrict__ Bt,
                                                int ldb,
                                                const float* __restrict__ bias,
                                                const unsigned short* __restrict__ resid,
                                                float* __restrict__ outF,
                                                unsigned short* __restrict__ outB,
                                                int N, int relu) {
    __shared__ unsigned short LDSb[3 * 2048 + 3 * 4096];   // 36 KB
    unsigned short* Al = LDSb;                 // [3][64*32]
    unsigned short* Bl = LDSb + 3 * 2048;      // [3][128*32]
    int tid = threadIdx.x;
    int w = tid >> 6, lane = tid & 63, q = lane >> 4, col = lane & 15;
    int wm = w & 1, wn = w >> 1;
    int m0 = blockIdx.x * 64;
    int n0 = blockIdx.y * 128;
    f32x4 acc[2][4] = {};
    int srow = lane >> 2;                      // 0..15
    int skq  = ((lane & 3) ^ ((srow >> 1) & 3)) * 8;
    const unsigned short* Ag0 = A  + (size_t)(m0 + w * 16 + srow) * lda + skq;
    const unsigned short* Bg0 = Bt + (size_t)(n0 + w * 32 + srow) * ldb + skq;
    const unsigned short* Bg1 = Bg0 + (size_t)16 * ldb;
    int rq = (q ^ ((col >> 1) & 3)) * 8;
#define G_STAGE(bf, kk) do { \
        gl_lds16(Ag0 + (kk), &Al[(bf) * 2048 + (w * 16) * 32]); \
        gl_lds16(Bg0 + (kk), &Bl[(bf) * 4096 + (w * 32) * 32]); \
        gl_lds16(Bg1 + (kk), &Bl[(bf) * 4096 + (w * 32 + 16) * 32]); \
    } while (0)
    G_STAGE(0, 0);
    G_STAGE(1, 32);
#pragma unroll
    for (int k0 = 0; k0 < KS; k0 += 32) {
        const int jb = (k0 >> 5) % 3;
        if (k0 + 32 < KS) { asm volatile("s_waitcnt vmcnt(3)" ::: "memory"); }
        else              { asm volatile("s_waitcnt vmcnt(0)" ::: "memory"); }
        __builtin_amdgcn_s_barrier();          // raw barrier: no implicit drain
        if (k0 + 64 < KS) G_STAGE((jb + 2) % 3, k0 + 64);
        bf16x8 a[2], b[4];
#pragma unroll
        for (int i = 0; i < 2; ++i)
            a[i] = ld8(&Al[jb * 2048 + (wm * 32 + i * 16 + col) * 32 + rq]);
#pragma unroll
        for (int j = 0; j < 4; ++j)
            b[j] = ld8(&Bl[jb * 4096 + (wn * 64 + j * 16 + col) * 32 + rq]);
#pragma unroll
        for (int i = 0; i < 2; ++i)
#pragma unroll
            for (int j = 0; j < 4; ++j)
                acc[i][j] = MFMA16(a[i], b[j], acc[i][j]);
        __builtin_amdgcn_sched_barrier(0);     // pin MFMA/lgkm before next bar
    }
#undef G_STAGE
    // ---- epilogue: LDS bounce -> coalesced stores -------------------------
    float* Cb = (float*)LDSb;                  // 32 x 132 f32 = 16.9 KB
    const int CLD = 132;                       // +4 pad: 2-way banks max
#pragma unroll
    for (int i = 0; i < 2; ++i) {
        __syncthreads();                       // prev use of LDS done
#pragma unroll
        for (int j = 0; j < 4; ++j)
#pragma unroll
            for (int r = 0; r < 4; ++r)
                Cb[(wm * 16 + q * 4 + r) * CLD + wn * 64 + j * 16 + col] = acc[i][j][r];
        __syncthreads();
        int row = tid >> 3;                    // 0..31
        int seg = (tid & 7) * 16;              // n-local start
        int mloc = (row & 15) + i * 16 + (row >> 4) * 32;
        int m = m0 + mloc;
        int n = n0 + seg;
        float vbuf[16];
#pragma unroll
        for (int u = 0; u < 16; ++u) vbuf[u] = Cb[row * CLD + seg + u];
        if (bias) {
#pragma unroll
            for (int u4 = 0; u4 < 4; ++u4) {
                float4 bb = *(const float4*)&bias[n + u4 * 4];
                vbuf[u4 * 4 + 0] += bb.x; vbuf[u4 * 4 + 1] += bb.y;
                vbuf[u4 * 4 + 2] += bb.z; vbuf[u4 * 4 + 3] += bb.w;
            }
        }
        if (resid) {                           // fused residual (bf16)
            u16x8 r0 = *(const u16x8*)&resid[(size_t)m * N + n];
            u16x8 r1 = *(const u16x8*)&resid[(size_t)m * N + n + 8];
#pragma unroll
            for (int u = 0; u < 8; ++u) {
                vbuf[u]     += b2f(r0[u]);
                vbuf[8 + u] += b2f(r1[u]);
            }
        }
        if (relu) {
#pragma unroll
            for (int u = 0; u < 16; ++u) vbuf[u] = fmaxf(vbuf[u], 0.f);
        }
        if (outF) {
#pragma unroll
            for (int u = 0; u < 16; u += 4)
                *(float4*)&outF[(size_t)m * N + n + u] = *(const float4*)&vbuf[u];
        }
        if (outB) {
            u16x8 o0, o1;
#pragma unroll
            for (int u = 0; u < 8; ++u) { o0[u] = f2b(vbuf[u]); o1[u] = f2b(vbuf[8 + u]); }
            *(u16x8*)&outB[(size_t)m * N + n] = o0;
            *(u16x8*)&outB[(size_t)m * N + n + 8] = o1;
        }
    }
}

// ---------------------------------------------------------------------------
// QKV GEMM, same 64x128 counted-vmcnt core (K=256). Epilogue scatter into the
// coalescing layouts: Qd/Kd [bh][db][t][16] (Q x QSCALE), Vc [bh][s/8][d][s%8].
__global__ __launch_bounds__(256) void gemm_qkv(const unsigned short* __restrict__ A,
                                                const unsigned short* __restrict__ Bt,
                                                unsigned short* __restrict__ Qd,
                                                unsigned short* __restrict__ Kd,
                                                unsigned short* __restrict__ Vc) {
    const int K = 256;
    __shared__ unsigned short LDSb[3 * 2048 + 3 * 4096];   // 36 KB
    unsigned short* Al = LDSb;
    unsigned short* Bl = LDSb + 3 * 2048;
    int tid = threadIdx.x;
    int w = tid >> 6, lane = tid & 63, q = lane >> 4, col = lane & 15;
    int wm = w & 1, wn = w >> 1;
    int m0 = blockIdx.x * 64;
    int n0 = blockIdx.y * 128;
    f32x4 acc[2][4] = {};
    int srow = lane >> 2;
    int skq  = ((lane & 3) ^ ((srow >> 1) & 3)) * 8;
    const unsigned short* Ag0 = A  + (size_t)(m0 + w * 16 + srow) * K + skq;
    const unsigned short* Bg0 = Bt + (size_t)(n0 + w * 32 + srow) * K + skq;
    const unsigned short* Bg1 = Bg0 + (size_t)16 * K;
    int rq = (q ^ ((col >> 1) & 3)) * 8;
#define G_STAGE(bf, kk) do { \
        gl_lds16(Ag0 + (kk), &Al[(bf) * 2048 + (w * 16) * 32]); \
        gl_lds16(Bg0 + (kk), &Bl[(bf) * 4096 + (w * 32) * 32]); \
        gl_lds16(Bg1 + (kk), &Bl[(bf) * 4096 + (w * 32 + 16) * 32]); \
    } while (0)
    G_STAGE(0, 0);
    G_STAGE(1, 32);
#pragma unroll
    for (int k0 = 0; k0 < K; k0 += 32) {
        const int jb = (k0 >> 5) % 3;
        if (k0 + 32 < K) { asm volatile("s_waitcnt vmcnt(3)" ::: "memory"); }
        else             { asm volatile("s_waitcnt vmcnt(0)" ::: "memory"); }
        __builtin_amdgcn_s_barrier();
        if (k0 + 64 < K) G_STAGE((jb + 2) % 3, k0 + 64);
        bf16x8 a[2], b[4];
#pragma unroll
        for (int i = 0; i < 2; ++i)
            a[i] = ld8(&Al[jb * 2048 + (wm * 32 + i * 16 + col) * 32 + rq]);
#pragma unroll
        for (int j = 0; j < 4; ++j)
            b[j] = ld8(&Bl[jb * 4096 + (wn * 64 + j * 16 + col) * 32 + rq]);
#pragma unroll
        for (int i = 0; i < 2; ++i)
#pragma unroll
            for (int j = 0; j < 4; ++j)
                acc[i][j] = MFMA16(a[i], b[j], acc[i][j]);
        __builtin_amdgcn_sched_barrier(0);
    }
#undef G_STAGE
#pragma unroll
    for (int i = 0; i < 2; ++i)
#pragma unroll
    for (int j = 0; j < 4; ++j) {
        int n = n0 + wn * 64 + j * 16 + col;
        int which = n >> 8, h = (n >> 5) & 7, d = n & 31;
        int m = m0 + wm * 32 + i * 16 + q * 4;
        int b = m >> 11, t = m & 2047;
        int bh = b * 8 + h;
        if (which == 0) {
            size_t qb = ((size_t)(bh * 2 + (d >> 4)) * TT + t) * 16 + (d & 15);
#pragma unroll
            for (int r = 0; r < 4; ++r)
                Qd[qb + r * 16] = f2b(acc[i][j][r] * QSCALE);
        } else if (which == 1) {
            size_t kb = ((size_t)(bh * 2 + (d >> 4)) * TT + t) * 16 + (d & 15);
#pragma unroll
            for (int r = 0; r < 4; ++r)
                Kd[kb + r * 16] = f2b(acc[i][j][r]);
        } else {
            uint2 pv;
            pv.x = pk_bf16(acc[i][j][0], acc[i][j][1]);
            pv.y = pk_bf16(acc[i][j][2], acc[i][j][3]);
            *(uint2*)&Vc[(((size_t)bh * 256 + (t >> 3)) * 32 + d) * 8 + (t & 7)] = pv;
        }
    }
}

// ---------------------------------------------------------------------------
// Pass 1 (+ fused V scale), one s-tile per block (grid bh x 64), 2-deep
// pipelined: colsum[s] = sum_{t>=s} exp2(.); then scale Vc columns in-place.
__global__ __launch_bounds__(256, 2) void attn_cols(const unsigned short* __restrict__ Qd,
                                                    const unsigned short* __restrict__ Kd,
                                                    unsigned short* __restrict__ Vc) {
    __shared__ float Lb[4][32];
    __shared__ float Linv[32];
    int tid = threadIdx.x;
    int w = tid >> 6, lane = tid & 63, hi = lane >> 5, l31 = lane & 31;
    int bh = blockIdx.x;
    int stile = blockIdx.y;                   // 0..63
    const unsigned short* Qb = Qd + ((size_t)bh * 2 * TT + l31) * 16 + hi * 8;
    const unsigned short* Kb = Kd + ((size_t)bh * 2 * TT + l31) * 16 + hi * 8;
    const f32x16 z16 = {};
    int sbase = stile * 32;
    bf16x8 a0 = ld8(Kb + (size_t)sbase * 16);             // d 0..15
    bf16x8 a1 = ld8(Kb + ((size_t)TT + sbase) * 16);      // d 16..31
    float acc[16] = {};
    int c = stile + w;
    bool diagP = (w == 0);                 // first chunk is diag for wave 0
    bf16x8 qP0, qP1, qQ0, qQ1;
    if (c < 64) {
        qP0 = ld8(Qb + (size_t)(c * 32) * 16);
        qP1 = ld8(Qb + ((size_t)TT + c * 32) * 16);
    }
    if (c + 4 < 64) {
        qQ0 = ld8(Qb + (size_t)((c + 4) * 32) * 16);
        qQ1 = ld8(Qb + ((size_t)TT + (c + 4) * 32) * 16);
    }
    while (c + 8 < 64) {                   // P, Q, and next-P all exist
        SETPRIO(1);
        f32x16 stP = MFMA32(a0, qP0, z16); stP = MFMA32(a1, qP1, stP);
        SETPRIO(0);
        qP0 = ld8(Qb + (size_t)((c + 8) * 32) * 16);        // next-P loads
        qP1 = ld8(Qb + ((size_t)TT + (c + 8) * 32) * 16);
        SETPRIO(1);
        f32x16 stQ = MFMA32(a0, qQ0, z16); stQ = MFMA32(a1, qQ1, stQ);
        SETPRIO(0);
        accum_exp(stP, diagP, hi, l31, acc); diagP = false; // VALU under stQ
        if (c + 12 < 64) {
            qQ0 = ld8(Qb + (size_t)((c + 12) * 32) * 16);   // next-Q loads
            qQ1 = ld8(Qb + ((size_t)TT + (c + 12) * 32) * 16);
        }
        accum_exp(stQ, false, hi, l31, acc);
        c += 8;
    }
    if (c < 64) {
        f32x16 stP = MFMA32(a0, qP0, z16); stP = MFMA32(a1, qP1, stP);
        accum_exp(stP, diagP, hi, l31, acc);
    }
    if (c + 4 < 64) {
        f32x16 stQ = MFMA32(a0, qQ0, z16); stQ = MFMA32(a1, qQ1, stQ);
        accum_exp(stQ, false, hi, l31, acc);
    }
#pragma unroll
    for (int off = 1; off <= 16; off <<= 1)
#pragma unroll
        for (int r = 0; r < 16; ++r) acc[r] += __shfl_xor(acc[r], off, 64);
    if (l31 == 0) {
#pragma unroll
        for (int r = 0; r < 16; ++r) {
            int s_local = (r & 3) + 8 * (r >> 2) + 4 * hi;
            Lb[w][s_local] = acc[r];
        }
    }
    __syncthreads();
    if (tid < 32)
        Linv[tid] = 1.0f / (Lb[0][tid] + Lb[1][tid] + Lb[2][tid] + Lb[3][tid]);
    __syncthreads();
    // scale Vc for s in [sbase, sbase+32): 4 sb x 32 d rows of 8
    if (tid < 128) {
        int sbl = tid >> 5;                // 0..3
        int d = tid & 31;
        size_t base = (((size_t)bh * 256 + stile * 4 + sbl) * 32 + d) * 8;
        u16x8 v = *(const u16x8*)&Vc[base];
        u16x8 o;
#pragma unroll
        for (int e = 0; e < 8; ++e) o[e] = f2b(b2f(v[e]) * Linv[sbl * 8 + e]);
        *(u16x8*)&Vc[base] = o;
    }
}

// ---------------------------------------------------------------------------
// Pass 2, one t-tile per block (grid bh x 64), 2-deep pipelined:
// O[t,:] = sum_{s<=t} exp2(q_t.k_s) * V'[s,:], xh = bf16(xn + O).
__global__ __launch_bounds__(256, 2) void attn_out(const unsigned short* __restrict__ Qd,
                                                   const unsigned short* __restrict__ Kd,
                                                   const unsigned short* __restrict__ Vc,
                                                   const unsigned short* __restrict__ xnb,
                                                   unsigned short* __restrict__ xh_bf) {
    __shared__ float Ob[4][16][36];            // 9216 B
    int tid = threadIdx.x;
    int w = tid >> 6, lane = tid & 63, hi = lane >> 5, l31 = lane & 31;
    int bh = blockIdx.x, b = bh >> 3, h = bh & 7;
    int tt = blockIdx.y;                       // 0..63
    const unsigned short* Kb = Kd + ((size_t)bh * 2 * TT + l31) * 16 + hi * 8;
    const unsigned short* Vb = Vc + (size_t)bh * 65536 + hi * 256 + l31 * 8;
    const unsigned short* Qbase = Qd + ((size_t)bh * 2 * TT + l31) * 16 + hi * 8;
    const f32x16 z16 = {};

    int tbase = tt * 32;
    bf16x8 q0 = ld8(Qbase + (size_t)tbase * 16);          // d 0..15
    bf16x8 q1 = ld8(Qbase + ((size_t)TT + tbase) * 16);   // d 16..31
    f32x16 acc = z16;                      // O[t=(r&3)+8(r>>2)+4hi][d=l31]

    int c = w;
    bf16x8 kP0, kP1, vP0, vP1, kQ0, kQ1, vQ0, vQ1;
    if (c <= tt) {
        kP0 = ld8(Kb + (size_t)c * 512);
        kP1 = ld8(Kb + (size_t)TT * 16 + (size_t)c * 512);
        vP0 = ld8(Vb + (size_t)c * 1024);
        vP1 = ld8(Vb + (size_t)c * 1024 + 512);
    }
    if (c + 4 <= tt) {
        kQ0 = ld8(Kb + (size_t)(c + 4) * 512);
        kQ1 = ld8(Kb + (size_t)TT * 16 + (size_t)(c + 4) * 512);
        vQ0 = ld8(Vb + (size_t)(c + 4) * 1024);
        vQ1 = ld8(Vb + (size_t)(c + 4) * 1024 + 512);
    }
    while (c + 8 <= tt) {                  // P,Q non-diag; next-P exists
        SETPRIO(1);
        f32x16 stP = MFMA32(kP0, q0, z16); stP = MFMA32(kP1, q1, stP);
        SETPRIO(0);
        kP0 = ld8(Kb + (size_t)(c + 8) * 512);              // next-P loads
        kP1 = ld8(Kb + (size_t)TT * 16 + (size_t)(c + 8) * 512);
        SETPRIO(1);
        f32x16 stQ = MFMA32(kQ0, q0, z16); stQ = MFMA32(kQ1, q1, stQ);
        SETPRIO(0);
        soft_pv(stP, vP0, vP1, false, hi, l31, acc);        // VALU under stQ
        vP0 = ld8(Vb + (size_t)(c + 8) * 1024);
        vP1 = ld8(Vb + (size_t)(c + 8) * 1024 + 512);
        if (c + 12 <= tt) {
            kQ0 = ld8(Kb + (size_t)(c + 12) * 512);         // next-Q loads
            kQ1 = ld8(Kb + (size_t)TT * 16 + (size_t)(c + 12) * 512);
        }
        soft_pv(stQ, vQ0, vQ1, false, hi, l31, acc);        // PV under loads
        if (c + 12 <= tt) {
            vQ0 = ld8(Vb + (size_t)(c + 12) * 1024);
            vQ1 = ld8(Vb + (size_t)(c + 12) * 1024 + 512);
        }
        c += 8;
    }
    if (c <= tt) {                         // tail chunk 1 (maybe diag)
        f32x16 stP = MFMA32(kP0, q0, z16); stP = MFMA32(kP1, q1, stP);
        soft_pv(stP, vP0, vP1, c == tt, hi, l31, acc);
    }
    if (c + 4 <= tt) {                     // tail chunk 2 (maybe diag)
        f32x16 stQ = MFMA32(kQ0, q0, z16); stQ = MFMA32(kQ1, q1, stQ);
        soft_pv(stQ, vQ0, vQ1, c + 4 == tt, hi, l31, acc);
    }

    // Two half-tile combines: t-rows [0,16) from acc r 0..7, then
    // t-rows [16,32) from acc r 8..15.
#pragma unroll
    for (int half = 0; half < 2; ++half) {
#pragma unroll
        for (int rr = 0; rr < 8; ++rr) {
            int r = half * 8 + rr;
            int t16 = (r & 3) + 8 * ((r >> 2) & 1) + 4 * hi;  // 0..15
            Ob[w][t16][l31] = acc[r];
        }
        __syncthreads();
        if (tid < 128) {                   // 16 rows x 8 col-quads
            int row = tid >> 3;
            int c4 = (tid & 7) * 4;
            float4 s0 = *(const float4*)&Ob[0][row][c4];
            float4 s1 = *(const float4*)&Ob[1][row][c4];
            float4 s2 = *(const float4*)&Ob[2][row][c4];
            float4 s3 = *(const float4*)&Ob[3][row][c4];
            size_t base = ((size_t)(b * TT) + tbase + half * 16 + row) * TE
                          + h * 32 + c4;
            u16x4 xv = *(const u16x4*)&xnb[base];
            u16x4 ob = { f2b(s0.x + s1.x + s2.x + s3.x + b2f(xv[0])),
                         f2b(s0.y + s1.y + s2.y + s3.y + b2f(xv[1])),
                         f2b(s0.z + s1.z + s2.z + s3.z + b2f(xv[2])),
                         f2b(s0.w + s1.w + s2.w + s3.w + b2f(xv[3])) };
            *(u16x4*)&xh_bf[base] = ob;
        }
        __syncthreads();                   // Ob reused next half
    }
}

// ---------------------------------------------------------------------------
extern "C" void kernel_launch(void* const* d_in, const int* in_sizes, int n_in,
                              void* d_out, int out_size, void* d_ws, size_t ws_size,
                              hipStream_t stream) {
    (void)in_sizes; (void)n_in; (void)out_size; (void)ws_size;
    const float* x     = (const float*)d_in[0];
    const float* wq    = (const float*)d_in[1];
    const float* wk    = (const float*)d_in[2];
    const float* wv    = (const float*)d_in[3];
    const float* w_lin = (const float*)d_in[4];
    const float* b_lin = (const float*)d_in[5];
    const float* g1    = (const float*)d_in[6];
    const float* beta1 = (const float*)d_in[7];
    const float* g2    = (const float*)d_in[8];
    const float* beta2 = (const float*)d_in[9];
    const float* w_f1  = (const float*)d_in[10];
    const float* b_f1  = (const float*)d_in[11];
    const float* w_f2  = (const float*)d_in[12];
    const float* b_f2  = (const float*)d_in[13];
    float* out = (float*)d_out;

    // Workspace layout (bytes), max 74 MB:
    char* ws = (char*)d_ws;
    unsigned short* Wqkv_t = (unsigned short*)(ws + 0);         //  384 KB
    unsigned short* Wlin_t = (unsigned short*)(ws + 393216);    //  128 KB
    unsigned short* Wf1_t  = (unsigned short*)(ws + 524288);    //  512 KB
    unsigned short* Wf2_t  = (unsigned short*)(ws + 1048576);   //  512 KB
    unsigned short* xn_bf  = (unsigned short*)(ws + 2097152);   //    8 MB [x2_bf aliases]
    unsigned short* Qbf    = (unsigned short*)(ws + 10485760);  //    8 MB ┐
    unsigned short* Kbf    = (unsigned short*)(ws + 18874368);  //    8 MB ├ h_bf (32 MB) aliases
    unsigned short* Vt     = (unsigned short*)(ws + 27262976);  //    8 MB │ (in-place scale)
    unsigned short* xh_bf  = (unsigned short*)(ws + 35651584);  //    8 MB ┘
    float*          Pp     = (float*)(ws + 44040192);           // 16.7 MB proj fp32 (single slice)
    unsigned short* x2_bf  = xn_bf;
    unsigned short* h_bf   = Qbf;   // 32 MB spanning Qbf..xh_bf (dead by FFN1)

    prep<<<4336, 256, 0, stream>>>(wq, wk, wv, w_lin, w_f1, w_f2,
                                   Wqkv_t, Wlin_t, Wf1_t, Wf2_t,
                                   x, g1, beta1, xn_bf);
    gemm_qkv<<<dim3(256, 6), 256, 0, stream>>>(xn_bf, Wqkv_t, Qbf, Kbf, Vt);
    attn_cols<<<dim3(64, 64), 256, 0, stream>>>(Qbf, Kbf, Vt);
    attn_out<<<dim3(64, 64), 256, 0, stream>>>(Qbf, Kbf, Vt, xn_bf, xh_bf);
    // proj: no split-K, single fp32 slice (bias folded into ln2_red)
    gemm_lds<256><<<dim3(256, 2), 256, 0, stream>>>(xh_bf, 256, Wlin_t, 256,
                                                    nullptr, nullptr, Pp, nullptr, 256, 0);
    ln2_red<<<4096, 256, 0, stream>>>(Pp, b_lin, g2, beta2, x2_bf);
    gemm_lds<256><<<dim3(256, 8), 256, 0, stream>>>(x2_bf, 256, Wf1_t, 256,
                                                    b_f1, nullptr, nullptr, h_bf, 1024, 1);
    // ffn2: K=1024 single pass, fused epilogue out = acc + b_f2 + x2 (fp32)
    gemm_lds<1024><<<dim3(256, 2), 256, 0, stream>>>(h_bf, 1024, Wf2_t, 1024,
                                                     b_f2, x2_bf, out, nullptr, 256, 0);
}